// Round 1
// 110.348 us; speedup vs baseline: 1.0690x; 1.0690x over previous
//
#include <hip/hip_runtime.h>
#include <math.h>

// YOLOv1 loss: predicts/targets (8192, 7, 7, 30) fp32 -> scalar.
// Memory-bound streaming reduction, roofline ~15.3 us @ 6.3 TB/s for 96.3 MB.
// v3: staging via async direct-to-LDS global_load_lds (width 16).
//   - 60 chunks of 1024 B per block (p: 0..29, t: 30..59), wave w stages
//     chunks [15w, 15w+15) -> exactly 15 uniform calls/wave, no VGPR round
//     trip, no per-iteration vmcnt serialization (prev loop had non-uniform
//     trip count: tid<128 -> 8 iters, tid>=128 -> 7).
//   - LDS layout stays LINEAR (global_load_lds writes wave-uniform base +
//     lane*16 — padding/swizzle would break it; compute-phase conflicts are
//     only 4-way on scalar ds_read, ~negligible vs HBM).
// One cell per thread, deterministic two-stage reduction (no atomics).

#define S7 7
#define CCH 30
#define CELLS_PER_BLOCK 256
#define N_CELLS (8192 * S7 * S7)             // 401408
#define N_BLOCKS (N_CELLS / CELLS_PER_BLOCK) // 1568 exactly
#define EPSV 1e-6f

__device__ __forceinline__ float iou_cxcywh(float acx, float acy, float aw, float ah,
                                            float bcx, float bcy, float bw, float bh) {
    float ax1 = acx - aw * 0.5f, ax2 = acx + aw * 0.5f;
    float ay1 = acy - ah * 0.5f, ay2 = acy + ah * 0.5f;
    float bx1 = bcx - bw * 0.5f, bx2 = bcx + bw * 0.5f;
    float by1 = bcy - bh * 0.5f, by2 = bcy + bh * 0.5f;
    float iw = fmaxf(fminf(ax2, bx2) - fmaxf(ax1, bx1), 0.0f);
    float ih = fmaxf(fminf(ay2, by2) - fmaxf(ay1, by1), 0.0f);
    float inter = iw * ih;
    float area_a = (ax2 - ax1) * (ay2 - ay1);
    float area_b = (bx2 - bx1) * (by2 - by1);
    return inter / (area_a + area_b - inter);
}

__global__ __launch_bounds__(256) void yolo_loss_partial(const float* __restrict__ pred,
                                                         const float* __restrict__ targ,
                                                         float* __restrict__ partial) {
    // p-tile: smem[0 .. 7680), t-tile: smem[7680 .. 15360)  (61440 B total)
    __shared__ float smem[2 * CELLS_PER_BLOCK * CCH];

    const int tid = threadIdx.x;
    const int lane = tid & 63;
    const int wid = tid >> 6;                 // wave 0..3
    const int block_cell0 = blockIdx.x * CELLS_PER_BLOCK;

    const float* gp = pred + (size_t)block_cell0 * CCH;  // 7680 floats
    const float* gt = targ + (size_t)block_cell0 * CCH;  // 7680 floats

    // ---- Stage: async global->LDS, 60 chunks x 1024 B, 15 per wave ----
    // chunk c < 30: p floats [c*256, c*256+256); c >= 30: t, LDS lands at
    // smem + c*256 which is exactly 7680 + (c-30)*256. All addresses
    // 16B-aligned (block base = 30720*blockIdx bytes, chunk = 1024B units).
#pragma unroll
    for (int i = 0; i < 15; ++i) {
        const int c = wid * 15 + i;           // wave-uniform
        const float* gsrc = (c < 30) ? (gp + c * 256 + lane * 4)
                                     : (gt + (c - 30) * 256 + lane * 4);
        float* ldst = smem + c * 256;         // wave-uniform base; HW adds lane*16
        __builtin_amdgcn_global_load_lds(
            (const __attribute__((address_space(1))) void*)gsrc,
            (__attribute__((address_space(3))) void*)ldst,
            16, 0, 0);
    }
    __syncthreads();   // compiler emits s_waitcnt vmcnt(0) before s_barrier

    // ---- Compute: one cell per thread ----
    const float* p = smem + tid * CCH;
    const float* t = smem + CELLS_PER_BLOCK * CCH + tid * CCH;
    const int cell = block_cell0 + tid;
    const int xy = cell % (S7 * S7);
    const float fx = (float)(xy % S7);
    const float fy = (float)(xy / S7);
    const float ratio = 1.0f / 7.0f;

    float px1 = p[0], py1 = p[1], pw1 = p[2], ph1 = p[3], pc1 = p[4];
    float px2 = p[5], py2 = p[6], pw2 = p[7], ph2 = p[8], pc2 = p[9];
    float tx = t[0], ty = t[1], tw = t[2], th = t[3], tc = t[4];
    bool obj = tc > 0.0f;

    float tcx = (tx + fx) * ratio, tcy = (ty + fy) * ratio;
    float iou1 = iou_cxcywh((px1 + fx) * ratio, (py1 + fy) * ratio, pw1, ph1,
                            tcx, tcy, tw, th);
    float iou2 = iou_cxcywh((px2 + fx) * ratio, (py2 + fy) * ratio, pw2, ph2,
                            tcx, tcy, tw, th);
    bool resp = iou1 > iou2;

    // class SSE (channels 10..29)
    float cls = 0.0f;
#pragma unroll
    for (int k = 10; k < 30; ++k) {
        float d = p[k] - t[k];
        cls += d * d;
    }

    float loss;
    if (obj) {
        float sx, sy, sw, sh, sc, siou;
        if (resp) { sx = px1; sy = py1; sw = pw1; sh = ph1; sc = pc1; siou = iou1; }
        else      { sx = px2; sy = py2; sw = pw2; sh = ph2; sc = pc2; siou = iou2; }
        float dx = sx - tx, dy = sy - ty;
        float dw = sqrtf(fmaxf(sw, EPSV)) - sqrtf(fmaxf(tw, EPSV));
        float dh = sqrtf(fmaxf(sh, EPSV)) - sqrtf(fmaxf(th, EPSV));
        float dc = sc - siou;
        loss = 5.0f * (dx * dx + dy * dy + dw * dw + dh * dh) + dc * dc + cls;
    } else {
        loss = 0.5f * (pc1 * pc1 + pc2 * pc2);
    }

    // ---- Block reduction: wave-64 shuffle, then 4 wave partials via LDS ----
    float v = loss;
#pragma unroll
    for (int off = 32; off > 0; off >>= 1) v += __shfl_down(v, off);

    __shared__ float red[4];
    if (lane == 0) red[wid] = v;
    __syncthreads();
    if (tid == 0) partial[blockIdx.x] = red[0] + red[1] + red[2] + red[3];
}

__global__ __launch_bounds__(256) void yolo_loss_final(const float* __restrict__ partial,
                                                       float* __restrict__ out) {
    float v = 0.0f;
    for (int i = threadIdx.x; i < N_BLOCKS; i += 256) v += partial[i];
#pragma unroll
    for (int off = 32; off > 0; off >>= 1) v += __shfl_down(v, off);

    __shared__ float red[4];
    const int lane = threadIdx.x & 63;
    const int wid = threadIdx.x >> 6;
    if (lane == 0) red[wid] = v;
    __syncthreads();
    if (threadIdx.x == 0) out[0] = red[0] + red[1] + red[2] + red[3];
}

extern "C" void kernel_launch(void* const* d_in, const int* in_sizes, int n_in,
                              void* d_out, int out_size, void* d_ws, size_t ws_size,
                              hipStream_t stream) {
    const float* predicts = (const float*)d_in[0];
    const float* targets  = (const float*)d_in[1];
    float* out = (float*)d_out;
    float* partial = (float*)d_ws;   // N_BLOCKS floats = 6272 B

    yolo_loss_partial<<<N_BLOCKS, 256, 0, stream>>>(predicts, targets, partial);
    yolo_loss_final<<<1, 256, 0, stream>>>(partial, out);
}